// Round 14
// baseline (135.743 us; speedup 1.0000x reference)
//
#include <hip/hip_runtime.h>
#include <math.h>

#define NEG_SLOPE 0.2f
#define BCAP 6144  // per-bucket capacity: mean 4096, sigma ~64 -> 32-sigma margin

typedef __attribute__((ext_vector_type(8))) short short8;
typedef __attribute__((ext_vector_type(4))) float f32x4;

static __device__ __forceinline__ float lrelu(float t) { return t > 0.f ? t : NEG_SLOPE * t; }
static __device__ __forceinline__ float bf2f(unsigned short h) {
  union { unsigned int i; float f; } c; c.i = ((unsigned int)h) << 16; return c.f;
}
static __device__ __forceinline__ unsigned short f2bf(float x) {
  union { float f; unsigned int i; } c; c.f = x;
  unsigned int r = (c.i + 0x7fffu + ((c.i >> 16) & 1u)) >> 16;
  return (unsigned short)r;
}
static __device__ __forceinline__ void unpack8(uint4 u, float* f) {
  unsigned int d[4] = {u.x, u.y, u.z, u.w};
#pragma unroll
  for (int i = 0; i < 4; ++i) {
    union { unsigned int i_; float f_; } lo, hi;
    lo.i_ = d[i] << 16;
    hi.i_ = d[i] & 0xffff0000u;
    f[2 * i] = lo.f_;
    f[2 * i + 1] = hi.f_;
  }
}

// ===== D1: fused bucket (blocks 0..nbb-1, single edge read) + cvtW (last 128 blocks) =====
__global__ __launch_bounds__(256) void k_prep(const int* __restrict__ srcI, const int* __restrict__ dstI,
                                              int* __restrict__ gcur, uint2* __restrict__ pairs, int e, int nbb,
                                              const float* __restrict__ Wl, const float* __restrict__ Wr,
                                              unsigned short* __restrict__ Wth, unsigned short* __restrict__ Wtl) {
  const int t = threadIdx.x;
  if ((int)blockIdx.x < nbb) {
    // ---- bucket 1024 edges by dst>>8; edges held in registers across both phases ----
    __shared__ int hist[256];
    __shared__ int base[256];
    int lo = blockIdx.x << 10;
    int hi = lo + 1024; if (hi > e) hi = e;
    hist[t] = 0;
    __syncthreads();
    int dreg[4], sreg[4];
    int cnt = 0;
#pragma unroll
    for (int u = 0; u < 4; ++u) {
      int i = lo + u * 256 + t;
      if (i < hi) {
        int d = dstI[i];
        dreg[cnt] = d;
        sreg[cnt] = srcI[i];
        atomicAdd(&hist[d >> 8], 1);
        ++cnt;
      }
    }
    __syncthreads();
    int h = hist[t];
    base[t] = h ? atomicAdd(&gcur[t], h) : 0;
    hist[t] = 0;
    __syncthreads();
    for (int u = 0; u < cnt; ++u) {
      int d = dreg[u];
      int b = d >> 8;
      int r = atomicAdd(&hist[b], 1);
      pairs[(size_t)b * BCAP + base[b] + r] = make_uint2((unsigned)d, (unsigned)sreg[u]);
    }
  } else {
    // ---- W transpose + split-bf16 convert ----
    int tid = ((int)blockIdx.x - nbb) * 256 + t;  // [0, 32768)
    int wsel = tid >> 14;
    int rem = tid & 16383;
    int k = rem >> 7, c = rem & 127;
    float v = wsel ? Wr[k * 128 + c] : Wl[k * 128 + c];
    unsigned short h = f2bf(v);
    unsigned short lo = f2bf(v - bf2f(h));
    Wth[(c + 128 * wsel) * 128 + k] = h;
    Wtl[(c + 128 * wsel) * 128 + k] = lo;
  }
}

// ================= D2: fused sortb (blocks 0..nbkt-1) + mfma GEMM (rest) =================
__global__ __launch_bounds__(256) void k_main(const uint2* __restrict__ pairs, const int* __restrict__ gcur,
                                              int* __restrict__ offs, int* __restrict__ csr,
                                              int n, int e, int nbkt,
                                              const float* __restrict__ X,
                                              const unsigned short* __restrict__ Wth,
                                              const unsigned short* __restrict__ Wtl,
                                              const float* __restrict__ bl, const float* __restrict__ br,
                                              const float* __restrict__ att,
                                              unsigned short* __restrict__ xlr,
                                              float* __restrict__ dl, float* __restrict__ dr) {
  __shared__ __align__(16) char lds[40960];
  const int t = threadIdx.x;
  if ((int)blockIdx.x < nbkt) {
    // ---- per-bucket low-byte counting sort -> offs + csr ----
    int* cnt = (int*)lds;
    int* pre = cnt + 256;
    int* bb = pre + 256;
    const int b = blockIdx.x;
    bb[t] = (t < nbkt) ? gcur[t] : 0;
    __syncthreads();
    for (int off = 1; off < 256; off <<= 1) {
      int u = (t >= off) ? bb[t - off] : 0;
      __syncthreads();
      bb[t] += u;
      __syncthreads();
    }
    const int mybase = (b == 0) ? 0 : bb[b - 1];
    const int mycnt = bb[b] - mybase;
    const uint2* bp = pairs + (size_t)b * BCAP;
    cnt[t] = 0;
    __syncthreads();
    for (int i = t; i < mycnt; i += 256) atomicAdd(&cnt[bp[i].x & 255], 1);
    __syncthreads();
    pre[t] = cnt[t];
    __syncthreads();
    for (int off = 1; off < 256; off <<= 1) {
      int u = (t >= off) ? pre[t - off] : 0;
      __syncthreads();
      pre[t] += u;
      __syncthreads();
    }
    int d = b * 256 + t;
    if (d < n) offs[d] = mybase + pre[t] - cnt[t];
    if (b == nbkt - 1 && t == 0) offs[n] = e;
    cnt[t] = pre[t] - cnt[t];
    __syncthreads();
    for (int i = t; i < mycnt; i += 256) {
      uint2 pr = bp[i];
      int r = atomicAdd(&cnt[pr.x & 255], 1);
      csr[mybase + r] = (int)pr.y;
    }
    return;
  }
  // ---- split-bf16 MFMA GEMM -> packed bf16 xlr[N][256] + 0.6*dl, 0.6*dr ----
  char* wh = lds;            // 16 KB
  char* wlo = lds + 16384;   // 16 KB
  char* xh = lds + 32768;    //  4 KB
  char* xo = lds + 36864;    //  4 KB
  const int w = t >> 6, l = t & 63;
  const int lr = l & 15, lg = l >> 4;
  const int R0 = (blockIdx.x - nbkt) * 64;

  f32x4 acc[4][4];
#pragma unroll
  for (int m = 0; m < 4; ++m)
#pragma unroll
    for (int nn = 0; nn < 4; ++nn) acc[m][nn] = (f32x4)(0.f);

  for (int k0 = 0; k0 < 128; k0 += 32) {
    if (k0) __syncthreads();
#pragma unroll
    for (int i = 0; i < 4; ++i) {
      int flat = t + i * 256;
      int col = flat >> 2, kc = flat & 3;
      int sw = (col & 3) ^ ((col >> 2) & 3);
      int off = col * 64 + ((kc ^ sw) << 4);
      *(uint4*)(wh + off) = *(const uint4*)(Wth + col * 128 + k0 + kc * 8);
      *(uint4*)(wlo + off) = *(const uint4*)(Wtl + col * 128 + k0 + kc * 8);
    }
    {
      int row = t >> 2, kc = t & 3;
      int r = R0 + row;
      float4 v0 = make_float4(0.f, 0.f, 0.f, 0.f), v1 = v0;
      if (r < n) {
        const float* p = X + (size_t)r * 128 + k0 + kc * 8;
        v0 = *(const float4*)p;
        v1 = *(const float4*)(p + 4);
      }
      float xs[8] = {v0.x, v0.y, v0.z, v0.w, v1.x, v1.y, v1.z, v1.w};
      unsigned int hi[4], lo[4];
#pragma unroll
      for (int i = 0; i < 4; ++i) {
        unsigned short h0 = f2bf(xs[2 * i]), h1 = f2bf(xs[2 * i + 1]);
        unsigned short l0 = f2bf(xs[2 * i] - bf2f(h0)), l1 = f2bf(xs[2 * i + 1] - bf2f(h1));
        hi[i] = (unsigned int)h0 | ((unsigned int)h1 << 16);
        lo[i] = (unsigned int)l0 | ((unsigned int)l1 << 16);
      }
      int sw = (row & 3) ^ ((row >> 2) & 3);
      int off = row * 64 + ((kc ^ sw) << 4);
      *(uint4*)(xh + off) = make_uint4(hi[0], hi[1], hi[2], hi[3]);
      *(uint4*)(xo + off) = make_uint4(lo[0], lo[1], lo[2], lo[3]);
    }
    __syncthreads();
    short8 axh[4], axl[4];
#pragma unroll
    for (int m = 0; m < 4; ++m) {
      int row = m * 16 + lr;
      int sw = (row & 3) ^ ((row >> 2) & 3);
      int off = row * 64 + ((lg ^ sw) << 4);
      axh[m] = *(const short8*)(xh + off);
      axl[m] = *(const short8*)(xo + off);
    }
#pragma unroll
    for (int nn = 0; nn < 4; ++nn) {
      int col = w * 64 + nn * 16 + lr;
      int sw = (col & 3) ^ ((col >> 2) & 3);
      int off = col * 64 + ((lg ^ sw) << 4);
      short8 bh = *(const short8*)(wh + off);
      short8 bo = *(const short8*)(wlo + off);
#pragma unroll
      for (int m = 0; m < 4; ++m) {
        acc[m][nn] = __builtin_amdgcn_mfma_f32_16x16x32_bf16(bh, axh[m], acc[m][nn], 0, 0, 0);
        acc[m][nn] = __builtin_amdgcn_mfma_f32_16x16x32_bf16(bh, axl[m], acc[m][nn], 0, 0, 0);
        acc[m][nn] = __builtin_amdgcn_mfma_f32_16x16x32_bf16(bo, axh[m], acc[m][nn], 0, 0, 0);
      }
    }
  }
  __syncthreads();  // LDS reuse for the dot reduction
  float* sred = (float*)lds;  // [4 waves][64 rows]
  float part[4];
#pragma unroll
  for (int m = 0; m < 4; ++m) {
    float pm = 0.f;
#pragma unroll
    for (int nn = 0; nn < 4; ++nn) {
      int colb = w * 64 + nn * 16 + lg * 4;
      const float* bp = (colb < 128) ? bl : br;
      float4 bv = *(const float4*)(bp + (colb & 127));
      float4 avv = *(const float4*)(att + (colb & 127));
      f32x4 o = acc[m][nn];
      float v0 = o[0] + bv.x, v1 = o[1] + bv.y, v2 = o[2] + bv.z, v3 = o[3] + bv.w;
      int row = R0 + m * 16 + lr;
      if (row < n) {
        uint2 pk;
        pk.x = (unsigned int)f2bf(v0) | ((unsigned int)f2bf(v1) << 16);
        pk.y = (unsigned int)f2bf(v2) | ((unsigned int)f2bf(v3) << 16);
        *(uint2*)(xlr + (size_t)row * 256 + colb) = pk;
      }
      pm += v0 * avv.x + v1 * avv.y + v2 * avv.z + v3 * avv.w;
    }
    pm += __shfl_xor(pm, 16, 64);
    pm += __shfl_xor(pm, 32, 64);
    part[m] = pm;
  }
  if (lg == 0) {
#pragma unroll
    for (int m = 0; m < 4; ++m) sred[w * 64 + m * 16 + lr] = part[m];
  }
  __syncthreads();
  if (t < 128) {
    int row = t & 63;
    int half = t >> 6;
    if (R0 + row < n) {
      float sum = sred[half * 128 + row] + sred[half * 128 + 64 + row];
      (half ? dr : dl)[R0 + row] = 0.6f * sum;
    }
  }
}

// ---------------- layer-1 GATv2: grid-stride persistent; wave per dst, 4x16 lanes ----------------
// e = dl[s] + dr[v] + 0.4*sum_c a_c*|xl[s,c]+xr[v,c]|   (dl,dr pre-scaled by 0.6)
__global__ __launch_bounds__(256) void k_gat1(const unsigned short* __restrict__ xlr,
                                              const float* __restrict__ dl, const float* __restrict__ dr,
                                              const float* __restrict__ att, const float* __restrict__ bias,
                                              const float* __restrict__ W2l, const float* __restrict__ b2l,
                                              const float* __restrict__ W2r, const float* __restrict__ b2r,
                                              const int* __restrict__ offs, const int* __restrict__ csr,
                                              float* __restrict__ hl, float* __restrict__ hr, int n) {
  const int gw = (blockIdx.x * 256 + threadIdx.x) >> 6;
  const int nw = (gridDim.x * 256) >> 6;
  const int lane = threadIdx.x & 63;
  const int g = lane >> 4;
  const int q = lane & 15;
  const int cb = q * 8;

  float av[8];
#pragma unroll
  for (int i = 0; i < 8; ++i) av[i] = att[cb + i];

  for (int v = gw; v < n; v += nw) {
    float xrf[8];
    unpack8(*(const uint4*)(xlr + (size_t)v * 256 + 128 + cb), xrf);
    const float c0 = dr[v];

    float acc[8] = {0.f, 0.f, 0.f, 0.f, 0.f, 0.f, 0.f, 0.f};
    float denom = 0.f;
    const int s0 = offs[v], s1 = offs[v + 1];

    if (g == 0) {  // self-loop
      float dls = dl[v];
      float xf[8];
      unpack8(*(const uint4*)(xlr + (size_t)v * 256 + cb), xf);
      float s2 = 0.f;
#pragma unroll
      for (int i = 0; i < 8; ++i) s2 = fmaf(av[i], fabsf(xf[i] + xrf[i]), s2);
      s2 += __shfl_xor(s2, 1, 64);
      s2 += __shfl_xor(s2, 2, 64);
      s2 += __shfl_xor(s2, 4, 64);
      s2 += __shfl_xor(s2, 8, 64);
      float pe = __expf(fmaf(0.4f, s2, dls + c0));
      denom += pe;
#pragma unroll
      for (int i = 0; i < 8; ++i) acc[i] = fmaf(pe, xf[i], acc[i]);
    }

    for (int j = s0 + g; j < s1; j += 4) {
      int s = csr[j];
      float dls = dl[s];
      float xf[8];
      unpack8(*(const uint4*)(xlr + (size_t)s * 256 + cb), xf);
      float s2 = 0.f;
#pragma unroll
      for (int i = 0; i < 8; ++i) s2 = fmaf(av[i], fabsf(xf[i] + xrf[i]), s2);
      s2 += __shfl_xor(s2, 1, 64);
      s2 += __shfl_xor(s2, 2, 64);
      s2 += __shfl_xor(s2, 4, 64);
      s2 += __shfl_xor(s2, 8, 64);
      float pe = __expf(fmaf(0.4f, s2, dls + c0));  // |e| small: no max needed
      denom += pe;
#pragma unroll
      for (int i = 0; i < 8; ++i) acc[i] = fmaf(pe, xf[i], acc[i]);
    }
#pragma unroll
    for (int off = 16; off <= 32; off <<= 1) {
#pragma unroll
      for (int i = 0; i < 8; ++i) acc[i] += __shfl_xor(acc[i], off, 64);
      denom += __shfl_xor(denom, off, 64);
    }
    float inv = 1.f / denom;
    float pl = 0.f, pr = 0.f;
#pragma unroll
    for (int i = 0; i < 8; ++i) {
      float h = fmaxf(acc[i] * inv + bias[cb + i], 0.f);
      pl += h * W2l[cb + i];
      pr += h * W2r[cb + i];
    }
#pragma unroll
    for (int off = 1; off <= 8; off <<= 1) {
      pl += __shfl_xor(pl, off, 64);
      pr += __shfl_xor(pr, off, 64);
    }
    if (lane == 0) {
      hl[v] = pl + b2l[0];
      hr[v] = pr + b2r[0];
    }
  }
}

// ---------------- layer-2 GATv2 (scalar) + sigmoid: 4 nodes/wave, 16 lanes each ----------------
__global__ __launch_bounds__(256) void k_gat2(const float* __restrict__ hl, const float* __restrict__ hr,
                                              const float* __restrict__ att2, const float* __restrict__ bias2,
                                              const int* __restrict__ offs, const int* __restrict__ csr,
                                              float* __restrict__ out, int n) {
  int wave = (blockIdx.x * 256 + threadIdx.x) >> 6;
  int lane = threadIdx.x & 63;
  const int g = lane >> 4;   // node sub-slot 0..3
  const int q = lane & 15;   // edge lane within slot
  int v = wave * 4 + g;
  if (v >= n) return;
  const float a2 = att2[0];
  const float hrv = hr[v];
  float d = 0.f, num = 0.f;
  if (q == 0) {  // self-loop
    float hlv = hl[v];
    float pe = __expf(a2 * lrelu(hlv + hrv));
    d += pe;
    num += pe * hlv;
  }
  const int s0 = offs[v], s1 = offs[v + 1];
  for (int j = s0 + q; j < s1; j += 16) {
    int s = csr[j];
    float hls = hl[s];
    float pe = __expf(a2 * lrelu(hls + hrv));
    d += pe;
    num += pe * hls;
  }
  // reduce within the 16-lane group (xor 1,2,4,8 stays inside the group)
#pragma unroll
  for (int off = 1; off <= 8; off <<= 1) {
    d += __shfl_xor(d, off, 64);
    num += __shfl_xor(num, off, 64);
  }
  if (q == 0) {
    float z = num / d + bias2[0];
    float o = 1.f / (1.f + __expf(-z));
    out[v] = o;
    out[n + v] = o;
    out[2 * n + v] = o;
  }
}

extern "C" void kernel_launch(void* const* d_in, const int* in_sizes, int n_in,
                              void* d_out, int out_size, void* d_ws, size_t ws_size,
                              hipStream_t stream) {
  const float* x     = (const float*)d_in[0];
  const int*   ei    = (const int*)d_in[1];
  const float* W1l   = (const float*)d_in[2];
  const float* b1l   = (const float*)d_in[3];
  const float* W1r   = (const float*)d_in[4];
  const float* b1r   = (const float*)d_in[5];
  const float* att1  = (const float*)d_in[6];
  const float* bias1 = (const float*)d_in[7];
  const float* W2l   = (const float*)d_in[8];
  const float* b2l   = (const float*)d_in[9];
  const float* W2r   = (const float*)d_in[10];
  const float* b2r   = (const float*)d_in[11];
  const float* att2  = (const float*)d_in[12];
  const float* bias2 = (const float*)d_in[13];
  float* out = (float*)d_out;

  const int N = in_sizes[0] / 128;
  const int E = in_sizes[1] / 2;
  const int* srcI = ei;
  const int* dstI = ei + E;
  const int NBKT = (N + 255) >> 8;    // 196
  const int NBB = (E + 1023) >> 10;   // bucket blocks

  // workspace carve (256-B aligned)
  char* w = (char*)d_ws;
  auto alloc = [&](size_t bytes) {
    char* p = w;
    w += (bytes + 255) & ~(size_t)255;
    return p;
  };
  int* gcur  = (int*)alloc(1024);
  uint2* pairs = (uint2*)alloc((size_t)NBKT * BCAP * 8);
  int* offs  = (int*)alloc((size_t)(N + 1) * 4);
  int* csr   = (int*)alloc((size_t)E * 4);
  unsigned short* Wth = (unsigned short*)alloc(256 * 128 * 2);
  unsigned short* Wtl = (unsigned short*)alloc(256 * 128 * 2);
  unsigned short* xlr = (unsigned short*)alloc((size_t)N * 256 * 2);
  float* dl  = (float*)alloc((size_t)N * 4);
  float* dr  = (float*)alloc((size_t)N * 4);
  float* hl  = (float*)alloc((size_t)N * 4);
  float* hr  = (float*)alloc((size_t)N * 4);

  const int LB = (N + 63) / 64;

  hipMemsetAsync(gcur, 0, 1024, stream);
  // D1: bucket (0..NBB-1, single edge read) + cvtW (NBB..NBB+127)
  k_prep<<<NBB + 128, 256, 0, stream>>>(srcI, dstI, gcur, pairs, E, NBB, W1l, W1r, Wth, Wtl);
  // D2: sortb (0..NBKT-1) + mfma (NBKT..NBKT+LB-1)
  k_main<<<NBKT + LB, 256, 0, stream>>>(pairs, gcur, offs, csr, N, E, NBKT,
                                        x, Wth, Wtl, b1l, b1r, att1, xlr, dl, dr);

  // gat1: persistent grid-stride (2048 blocks = 8 waves/CU)
  k_gat1<<<2048, 256, 0, stream>>>(xlr, dl, dr, att1, bias1, W2l, b2l, W2r, b2r, offs, csr, hl, hr, N);
  const int GB2 = (N + 15) / 16;  // 4 nodes per wave
  k_gat2<<<GB2, 256, 0, stream>>>(hl, hr, att2, bias2, offs, csr, out, N);
}

// Round 15
// 114.395 us; speedup vs baseline: 1.1866x; 1.1866x over previous
//
#include <hip/hip_runtime.h>
#include <math.h>

#define NEG_SLOPE 0.2f
#define BCAP 6144  // per-bucket capacity: mean 4096, sigma ~64 -> 32-sigma margin

typedef __attribute__((ext_vector_type(8))) short short8;
typedef __attribute__((ext_vector_type(4))) float f32x4;

static __device__ __forceinline__ float lrelu(float t) { return t > 0.f ? t : NEG_SLOPE * t; }
static __device__ __forceinline__ float bf2f(unsigned short h) {
  union { unsigned int i; float f; } c; c.i = ((unsigned int)h) << 16; return c.f;
}
static __device__ __forceinline__ unsigned short f2bf(float x) {
  union { float f; unsigned int i; } c; c.f = x;
  unsigned int r = (c.i + 0x7fffu + ((c.i >> 16) & 1u)) >> 16;
  return (unsigned short)r;
}
static __device__ __forceinline__ void unpack8(uint4 u, float* f) {
  unsigned int d[4] = {u.x, u.y, u.z, u.w};
#pragma unroll
  for (int i = 0; i < 4; ++i) {
    union { unsigned int i_; float f_; } lo, hi;
    lo.i_ = d[i] << 16;
    hi.i_ = d[i] & 0xffff0000u;
    f[2 * i] = lo.f_;
    f[2 * i + 1] = hi.f_;
  }
}

// ===== D1: fused bucket (blocks 0..nbb-1, single edge read) + cvtW (last 128 blocks) =====
__global__ __launch_bounds__(256) void k_prep(const int* __restrict__ srcI, const int* __restrict__ dstI,
                                              int* __restrict__ gcur, uint2* __restrict__ pairs, int e, int nbb,
                                              const float* __restrict__ Wl, const float* __restrict__ Wr,
                                              unsigned short* __restrict__ Wth, unsigned short* __restrict__ Wtl) {
  const int t = threadIdx.x;
  if ((int)blockIdx.x < nbb) {
    // ---- bucket 1024 edges by dst>>8; edges held in registers across both phases ----
    __shared__ int hist[256];
    __shared__ int base[256];
    int lo = blockIdx.x << 10;
    int hi = lo + 1024; if (hi > e) hi = e;
    hist[t] = 0;
    __syncthreads();
    int dreg[4], sreg[4];
    int cnt = 0;
#pragma unroll
    for (int u = 0; u < 4; ++u) {
      int i = lo + u * 256 + t;
      if (i < hi) {
        int d = dstI[i];
        dreg[cnt] = d;
        sreg[cnt] = srcI[i];
        atomicAdd(&hist[d >> 8], 1);
        ++cnt;
      }
    }
    __syncthreads();
    int h = hist[t];
    base[t] = h ? atomicAdd(&gcur[t], h) : 0;
    hist[t] = 0;
    __syncthreads();
    for (int u = 0; u < cnt; ++u) {
      int d = dreg[u];
      int b = d >> 8;
      int r = atomicAdd(&hist[b], 1);
      pairs[(size_t)b * BCAP + base[b] + r] = make_uint2((unsigned)d, (unsigned)sreg[u]);
    }
  } else {
    // ---- W transpose + split-bf16 convert ----
    int tid = ((int)blockIdx.x - nbb) * 256 + t;  // [0, 32768)
    int wsel = tid >> 14;
    int rem = tid & 16383;
    int k = rem >> 7, c = rem & 127;
    float v = wsel ? Wr[k * 128 + c] : Wl[k * 128 + c];
    unsigned short h = f2bf(v);
    unsigned short lo = f2bf(v - bf2f(h));
    Wth[(c + 128 * wsel) * 128 + k] = h;
    Wtl[(c + 128 * wsel) * 128 + k] = lo;
  }
}

// ================= D2: fused sortb (blocks 0..nbkt-1) + mfma GEMM (rest) =================
__global__ __launch_bounds__(256) void k_main(const uint2* __restrict__ pairs, const int* __restrict__ gcur,
                                              int* __restrict__ offs, int* __restrict__ csr,
                                              int n, int e, int nbkt,
                                              const float* __restrict__ X,
                                              const unsigned short* __restrict__ Wth,
                                              const unsigned short* __restrict__ Wtl,
                                              const float* __restrict__ bl, const float* __restrict__ br,
                                              const float* __restrict__ att,
                                              unsigned short* __restrict__ xlr,
                                              float* __restrict__ dl, float* __restrict__ dr) {
  __shared__ __align__(16) char lds[40960];
  const int t = threadIdx.x;
  if ((int)blockIdx.x < nbkt) {
    // ---- per-bucket low-byte counting sort -> offs + csr ----
    int* cnt = (int*)lds;
    int* pre = cnt + 256;
    int* bb = pre + 256;
    const int b = blockIdx.x;
    bb[t] = (t < nbkt) ? gcur[t] : 0;
    __syncthreads();
    for (int off = 1; off < 256; off <<= 1) {
      int u = (t >= off) ? bb[t - off] : 0;
      __syncthreads();
      bb[t] += u;
      __syncthreads();
    }
    const int mybase = (b == 0) ? 0 : bb[b - 1];
    const int mycnt = bb[b] - mybase;
    const uint2* bp = pairs + (size_t)b * BCAP;
    cnt[t] = 0;
    __syncthreads();
    for (int i = t; i < mycnt; i += 256) atomicAdd(&cnt[bp[i].x & 255], 1);
    __syncthreads();
    pre[t] = cnt[t];
    __syncthreads();
    for (int off = 1; off < 256; off <<= 1) {
      int u = (t >= off) ? pre[t - off] : 0;
      __syncthreads();
      pre[t] += u;
      __syncthreads();
    }
    int d = b * 256 + t;
    if (d < n) offs[d] = mybase + pre[t] - cnt[t];
    if (b == nbkt - 1 && t == 0) offs[n] = e;
    cnt[t] = pre[t] - cnt[t];
    __syncthreads();
    for (int i = t; i < mycnt; i += 256) {
      uint2 pr = bp[i];
      int r = atomicAdd(&cnt[pr.x & 255], 1);
      csr[mybase + r] = (int)pr.y;
    }
    return;
  }
  // ---- split-bf16 MFMA GEMM -> packed bf16 xlr[N][256] + 0.6*dl, 0.6*dr ----
  char* wh = lds;            // 16 KB
  char* wlo = lds + 16384;   // 16 KB
  char* xh = lds + 32768;    //  4 KB
  char* xo = lds + 36864;    //  4 KB
  const int w = t >> 6, l = t & 63;
  const int lr = l & 15, lg = l >> 4;
  const int R0 = (blockIdx.x - nbkt) * 64;

  f32x4 acc[4][4];
#pragma unroll
  for (int m = 0; m < 4; ++m)
#pragma unroll
    for (int nn = 0; nn < 4; ++nn) acc[m][nn] = (f32x4)(0.f);

  for (int k0 = 0; k0 < 128; k0 += 32) {
    if (k0) __syncthreads();
#pragma unroll
    for (int i = 0; i < 4; ++i) {
      int flat = t + i * 256;
      int col = flat >> 2, kc = flat & 3;
      int sw = (col & 3) ^ ((col >> 2) & 3);
      int off = col * 64 + ((kc ^ sw) << 4);
      *(uint4*)(wh + off) = *(const uint4*)(Wth + col * 128 + k0 + kc * 8);
      *(uint4*)(wlo + off) = *(const uint4*)(Wtl + col * 128 + k0 + kc * 8);
    }
    {
      int row = t >> 2, kc = t & 3;
      int r = R0 + row;
      float4 v0 = make_float4(0.f, 0.f, 0.f, 0.f), v1 = v0;
      if (r < n) {
        const float* p = X + (size_t)r * 128 + k0 + kc * 8;
        v0 = *(const float4*)p;
        v1 = *(const float4*)(p + 4);
      }
      float xs[8] = {v0.x, v0.y, v0.z, v0.w, v1.x, v1.y, v1.z, v1.w};
      unsigned int hi[4], lo[4];
#pragma unroll
      for (int i = 0; i < 4; ++i) {
        unsigned short h0 = f2bf(xs[2 * i]), h1 = f2bf(xs[2 * i + 1]);
        unsigned short l0 = f2bf(xs[2 * i] - bf2f(h0)), l1 = f2bf(xs[2 * i + 1] - bf2f(h1));
        hi[i] = (unsigned int)h0 | ((unsigned int)h1 << 16);
        lo[i] = (unsigned int)l0 | ((unsigned int)l1 << 16);
      }
      int sw = (row & 3) ^ ((row >> 2) & 3);
      int off = row * 64 + ((kc ^ sw) << 4);
      *(uint4*)(xh + off) = make_uint4(hi[0], hi[1], hi[2], hi[3]);
      *(uint4*)(xo + off) = make_uint4(lo[0], lo[1], lo[2], lo[3]);
    }
    __syncthreads();
    short8 axh[4], axl[4];
#pragma unroll
    for (int m = 0; m < 4; ++m) {
      int row = m * 16 + lr;
      int sw = (row & 3) ^ ((row >> 2) & 3);
      int off = row * 64 + ((lg ^ sw) << 4);
      axh[m] = *(const short8*)(xh + off);
      axl[m] = *(const short8*)(xo + off);
    }
#pragma unroll
    for (int nn = 0; nn < 4; ++nn) {
      int col = w * 64 + nn * 16 + lr;
      int sw = (col & 3) ^ ((col >> 2) & 3);
      int off = col * 64 + ((lg ^ sw) << 4);
      short8 bh = *(const short8*)(wh + off);
      short8 bo = *(const short8*)(wlo + off);
#pragma unroll
      for (int m = 0; m < 4; ++m) {
        acc[m][nn] = __builtin_amdgcn_mfma_f32_16x16x32_bf16(bh, axh[m], acc[m][nn], 0, 0, 0);
        acc[m][nn] = __builtin_amdgcn_mfma_f32_16x16x32_bf16(bh, axl[m], acc[m][nn], 0, 0, 0);
        acc[m][nn] = __builtin_amdgcn_mfma_f32_16x16x32_bf16(bo, axh[m], acc[m][nn], 0, 0, 0);
      }
    }
  }
  __syncthreads();  // LDS reuse for the dot reduction
  float* sred = (float*)lds;  // [4 waves][64 rows]
  float part[4];
#pragma unroll
  for (int m = 0; m < 4; ++m) {
    float pm = 0.f;
#pragma unroll
    for (int nn = 0; nn < 4; ++nn) {
      int colb = w * 64 + nn * 16 + lg * 4;
      const float* bp = (colb < 128) ? bl : br;
      float4 bv = *(const float4*)(bp + (colb & 127));
      float4 avv = *(const float4*)(att + (colb & 127));
      f32x4 o = acc[m][nn];
      float v0 = o[0] + bv.x, v1 = o[1] + bv.y, v2 = o[2] + bv.z, v3 = o[3] + bv.w;
      int row = R0 + m * 16 + lr;
      if (row < n) {
        uint2 pk;
        pk.x = (unsigned int)f2bf(v0) | ((unsigned int)f2bf(v1) << 16);
        pk.y = (unsigned int)f2bf(v2) | ((unsigned int)f2bf(v3) << 16);
        *(uint2*)(xlr + (size_t)row * 256 + colb) = pk;
      }
      pm += v0 * avv.x + v1 * avv.y + v2 * avv.z + v3 * avv.w;
    }
    pm += __shfl_xor(pm, 16, 64);
    pm += __shfl_xor(pm, 32, 64);
    part[m] = pm;
  }
  if (lg == 0) {
#pragma unroll
    for (int m = 0; m < 4; ++m) sred[w * 64 + m * 16 + lr] = part[m];
  }
  __syncthreads();
  if (t < 128) {
    int row = t & 63;
    int half = t >> 6;
    if (R0 + row < n) {
      float sum = sred[half * 128 + row] + sred[half * 128 + 64 + row];
      (half ? dr : dl)[R0 + row] = 0.6f * sum;
    }
  }
}

// ---------------- layer-1 GATv2: wave per dst, 4 edge-groups x 16 lanes (R13-exact, VGPR 32) ----------------
// e = dl[s] + dr[v] + 0.4*sum_c a_c*|xl[s,c]+xr[v,c]|   (dl,dr pre-scaled by 0.6)
__global__ __launch_bounds__(256) void k_gat1(const unsigned short* __restrict__ xlr,
                                              const float* __restrict__ dl, const float* __restrict__ dr,
                                              const float* __restrict__ att, const float* __restrict__ bias,
                                              const float* __restrict__ W2l, const float* __restrict__ b2l,
                                              const float* __restrict__ W2r, const float* __restrict__ b2r,
                                              const int* __restrict__ offs, const int* __restrict__ csr,
                                              float* __restrict__ hl, float* __restrict__ hr, int n) {
  int wave = (blockIdx.x * 256 + threadIdx.x) >> 6;
  int lane = threadIdx.x & 63;
  if (wave >= n) return;
  const int v = wave;
  const int g = lane >> 4;
  const int q = lane & 15;
  const int cb = q * 8;

  float xrf[8];
  unpack8(*(const uint4*)(xlr + (size_t)v * 256 + 128 + cb), xrf);
  float av[8];
#pragma unroll
  for (int i = 0; i < 8; ++i) av[i] = att[cb + i];
  const float c0 = dr[v];

  float acc[8] = {0.f, 0.f, 0.f, 0.f, 0.f, 0.f, 0.f, 0.f};
  float denom = 0.f;
  const int s0 = offs[v], s1 = offs[v + 1];

  if (g == 0) {  // self-loop
    float dls = dl[v];
    float xf[8];
    unpack8(*(const uint4*)(xlr + (size_t)v * 256 + cb), xf);
    float s2 = 0.f;
#pragma unroll
    for (int i = 0; i < 8; ++i) s2 = fmaf(av[i], fabsf(xf[i] + xrf[i]), s2);
    s2 += __shfl_xor(s2, 1, 64);
    s2 += __shfl_xor(s2, 2, 64);
    s2 += __shfl_xor(s2, 4, 64);
    s2 += __shfl_xor(s2, 8, 64);
    float pe = __expf(fmaf(0.4f, s2, dls + c0));
    denom += pe;
#pragma unroll
    for (int i = 0; i < 8; ++i) acc[i] = fmaf(pe, xf[i], acc[i]);
  }

  for (int j = s0 + g; j < s1; j += 4) {
    int s = csr[j];
    float dls = dl[s];
    float xf[8];
    unpack8(*(const uint4*)(xlr + (size_t)s * 256 + cb), xf);
    float s2 = 0.f;
#pragma unroll
    for (int i = 0; i < 8; ++i) s2 = fmaf(av[i], fabsf(xf[i] + xrf[i]), s2);
    s2 += __shfl_xor(s2, 1, 64);
    s2 += __shfl_xor(s2, 2, 64);
    s2 += __shfl_xor(s2, 4, 64);
    s2 += __shfl_xor(s2, 8, 64);
    float pe = __expf(fmaf(0.4f, s2, dls + c0));  // |e| small: no max needed
    denom += pe;
#pragma unroll
    for (int i = 0; i < 8; ++i) acc[i] = fmaf(pe, xf[i], acc[i]);
  }
#pragma unroll
  for (int off = 16; off <= 32; off <<= 1) {
#pragma unroll
    for (int i = 0; i < 8; ++i) acc[i] += __shfl_xor(acc[i], off, 64);
    denom += __shfl_xor(denom, off, 64);
  }
  float inv = 1.f / denom;
  float pl = 0.f, pr = 0.f;
#pragma unroll
  for (int i = 0; i < 8; ++i) {
    float h = fmaxf(acc[i] * inv + bias[cb + i], 0.f);
    pl += h * W2l[cb + i];
    pr += h * W2r[cb + i];
  }
#pragma unroll
  for (int off = 1; off <= 8; off <<= 1) {
    pl += __shfl_xor(pl, off, 64);
    pr += __shfl_xor(pr, off, 64);
  }
  if (lane == 0) {
    hl[v] = pl + b2l[0];
    hr[v] = pr + b2r[0];
  }
}

// ---------------- layer-2 GATv2 (scalar) + sigmoid: 4 nodes/wave, 16 lanes each ----------------
__global__ __launch_bounds__(256) void k_gat2(const float* __restrict__ hl, const float* __restrict__ hr,
                                              const float* __restrict__ att2, const float* __restrict__ bias2,
                                              const int* __restrict__ offs, const int* __restrict__ csr,
                                              float* __restrict__ out, int n) {
  int wave = (blockIdx.x * 256 + threadIdx.x) >> 6;
  int lane = threadIdx.x & 63;
  const int g = lane >> 4;   // node sub-slot 0..3
  const int q = lane & 15;   // edge lane within slot
  int v = wave * 4 + g;
  if (v >= n) return;
  const float a2 = att2[0];
  const float hrv = hr[v];
  float d = 0.f, num = 0.f;
  if (q == 0) {  // self-loop
    float hlv = hl[v];
    float pe = __expf(a2 * lrelu(hlv + hrv));
    d += pe;
    num += pe * hlv;
  }
  const int s0 = offs[v], s1 = offs[v + 1];
  for (int j = s0 + q; j < s1; j += 16) {
    int s = csr[j];
    float hls = hl[s];
    float pe = __expf(a2 * lrelu(hls + hrv));
    d += pe;
    num += pe * hls;
  }
  // reduce within the 16-lane group (xor 1,2,4,8 stays inside the group)
#pragma unroll
  for (int off = 1; off <= 8; off <<= 1) {
    d += __shfl_xor(d, off, 64);
    num += __shfl_xor(num, off, 64);
  }
  if (q == 0) {
    float z = num / d + bias2[0];
    float o = 1.f / (1.f + __expf(-z));
    out[v] = o;
    out[n + v] = o;
    out[2 * n + v] = o;
  }
}

extern "C" void kernel_launch(void* const* d_in, const int* in_sizes, int n_in,
                              void* d_out, int out_size, void* d_ws, size_t ws_size,
                              hipStream_t stream) {
  const float* x     = (const float*)d_in[0];
  const int*   ei    = (const int*)d_in[1];
  const float* W1l   = (const float*)d_in[2];
  const float* b1l   = (const float*)d_in[3];
  const float* W1r   = (const float*)d_in[4];
  const float* b1r   = (const float*)d_in[5];
  const float* att1  = (const float*)d_in[6];
  const float* bias1 = (const float*)d_in[7];
  const float* W2l   = (const float*)d_in[8];
  const float* b2l   = (const float*)d_in[9];
  const float* W2r   = (const float*)d_in[10];
  const float* b2r   = (const float*)d_in[11];
  const float* att2  = (const float*)d_in[12];
  const float* bias2 = (const float*)d_in[13];
  float* out = (float*)d_out;

  const int N = in_sizes[0] / 128;
  const int E = in_sizes[1] / 2;
  const int* srcI = ei;
  const int* dstI = ei + E;
  const int NBKT = (N + 255) >> 8;    // 196
  const int NBB = (E + 1023) >> 10;   // bucket blocks

  // workspace carve (256-B aligned)
  char* w = (char*)d_ws;
  auto alloc = [&](size_t bytes) {
    char* p = w;
    w += (bytes + 255) & ~(size_t)255;
    return p;
  };
  int* gcur  = (int*)alloc(1024);
  uint2* pairs = (uint2*)alloc((size_t)NBKT * BCAP * 8);
  int* offs  = (int*)alloc((size_t)(N + 1) * 4);
  int* csr   = (int*)alloc((size_t)E * 4);
  unsigned short* Wth = (unsigned short*)alloc(256 * 128 * 2);
  unsigned short* Wtl = (unsigned short*)alloc(256 * 128 * 2);
  unsigned short* xlr = (unsigned short*)alloc((size_t)N * 256 * 2);
  float* dl  = (float*)alloc((size_t)N * 4);
  float* dr  = (float*)alloc((size_t)N * 4);
  float* hl  = (float*)alloc((size_t)N * 4);
  float* hr  = (float*)alloc((size_t)N * 4);

  const int LB = (N + 63) / 64;

  hipMemsetAsync(gcur, 0, 1024, stream);
  // D1: bucket (0..NBB-1, single edge read) + cvtW (NBB..NBB+127)
  k_prep<<<NBB + 128, 256, 0, stream>>>(srcI, dstI, gcur, pairs, E, NBB, W1l, W1r, Wth, Wtl);
  // D2: sortb (0..NBKT-1) + mfma (NBKT..NBKT+LB-1)
  k_main<<<NBKT + LB, 256, 0, stream>>>(pairs, gcur, offs, csr, N, E, NBKT,
                                        x, Wth, Wtl, b1l, b1r, att1, xlr, dl, dr);

  const int GB = (N + 3) / 4;  // 4 waves (nodes) per 256-thread block
  k_gat1<<<GB, 256, 0, stream>>>(xlr, dl, dr, att1, bias1, W2l, b2l, W2r, b2r, offs, csr, hl, hr, N);
  const int GB2 = (N + 15) / 16;  // 4 nodes per wave
  k_gat2<<<GB2, 256, 0, stream>>>(hl, hr, att2, bias2, offs, csr, out, N);
}